// Round 1
// baseline (1091.322 us; speedup 1.0000x reference)
//
#include <hip/hip_runtime.h>
#include <math.h>

#define D_DIM 256
#define K_NUM 4096
#define N_ROWS 32768

// ---------------- vv[k] = sum_d V[d][k]^2 (sequential adds, rounding irrelevant:
// vv ~ 8.5e-3, its ulp ~1e-9 << the 3e-5 grid of the final distance add) -------
__global__ __launch_bounds__(256) void vq_vv(const float* __restrict__ V,
                                             float* __restrict__ vv) {
  int k = blockIdx.x * 256 + threadIdx.x;
  float acc = 0.0f;
  for (int d = 0; d < D_DIM; ++d) {
    float v = V[(size_t)d * K_NUM + k];
    acc = __fadd_rn(acc, __fmul_rn(v, v));
  }
  vv[k] = acc;
}

// numpy pairwise sum of squares over 128 contiguous floats:
// 8 accumulators unrolled-by-8, combined ((r0+r1)+(r2+r3)) + ((r4+r5)+(r6+r7))
__device__ inline float np_pw128_sumsq(const float* __restrict__ p) {
  float r[8];
#pragma unroll
  for (int j = 0; j < 8; ++j) r[j] = __fmul_rn(p[j], p[j]);
#pragma unroll
  for (int i = 8; i < 128; i += 8) {
#pragma unroll
    for (int j = 0; j < 8; ++j)
      r[j] = __fadd_rn(r[j], __fmul_rn(p[i + j], p[i + j]));
  }
  float t01 = __fadd_rn(r[0], r[1]);
  float t23 = __fadd_rn(r[2], r[3]);
  float t45 = __fadd_rn(r[4], r[5]);
  float t67 = __fadd_rn(r[6], r[7]);
  return __fadd_rn(__fadd_rn(t01, t23), __fadd_rn(t45, t67));
}

// ---------------- fused GEMM + argmin ----------------
// Block: 64 rows x full K. 256 threads = (tx 0..31, ty 0..7), micro-tile 8x8.
// K-tiles of 256 cols, d-chunks of 16.
__global__ __launch_bounds__(256, 2) void vq_main(const float* __restrict__ A,
                                                  const float* __restrict__ B,
                                                  const float* __restrict__ vv,
                                                  float* __restrict__ idx_out) {
  __shared__ float As[16][64];    // [d][row]  4 KB
  __shared__ float Bs[16][256];   // [d][col] 16 KB
  __shared__ float vvs[256];
  __shared__ float xxs[64];

  const int tid = threadIdx.x;
  const int tx = tid & 31;
  const int ty = tid >> 5;
  const int row0 = blockIdx.x * 64;

  // ||x_row||^2 with numpy's exact pairwise structure (256 = 128 + 128)
  if (tid < 64) {
    const float* ap = A + (size_t)(row0 + tid) * D_DIM;
    xxs[tid] = __fadd_rn(np_pw128_sumsq(ap), np_pw128_sumsq(ap + 128));
  }
  __syncthreads();

  float xr[8];
#pragma unroll
  for (int i = 0; i < 8; ++i) xr[i] = xxs[ty * 8 + i];

  float best[8];
  int bidx[8];
#pragma unroll
  for (int i = 0; i < 8; ++i) { best[i] = INFINITY; bidx[i] = 0; }

  const int arow = tid >> 2;  // A staging: row
  const int ac4  = tid & 3;   // A staging: float4 slot in 16-d chunk
  const int bdd  = tid >> 4;  // B staging: d row
  const int bg   = tid & 15;

  for (int kt = 0; kt < 16; ++kt) {
    __syncthreads();  // protect vvs (and last Bs) from previous-iteration readers
    vvs[tid] = vv[kt * 256 + tid];

    float acc[8][8];
#pragma unroll
    for (int i = 0; i < 8; ++i)
#pragma unroll
      for (int j = 0; j < 8; ++j) acc[i][j] = 0.0f;

    for (int dc = 0; dc < 16; ++dc) {
      __syncthreads();
      {  // A chunk, transposed store [d][row]
        float4 av = *(const float4*)(A + (size_t)(row0 + arow) * D_DIM +
                                     dc * 16 + ac4 * 4);
        As[ac4 * 4 + 0][arow] = av.x;
        As[ac4 * 4 + 1][arow] = av.y;
        As[ac4 * 4 + 2][arow] = av.z;
        As[ac4 * 4 + 3][arow] = av.w;
      }
      {  // B chunk [16][256], coalesced 256B per (dd,j) group
        const float* bp = B + (size_t)(dc * 16 + bdd) * K_NUM + kt * 256;
#pragma unroll
        for (int j = 0; j < 4; ++j) {
          float4 bv = *(const float4*)(bp + j * 64 + bg * 4);
          *(float4*)&Bs[bdd][j * 64 + bg * 4] = bv;
        }
      }
      __syncthreads();
#pragma unroll
      for (int dd = 0; dd < 16; ++dd) {
        float4 alo = *(const float4*)&As[dd][ty * 8];
        float4 ahi = *(const float4*)&As[dd][ty * 8 + 4];
        // B fragment split into two stride-16B groups -> conflict-free banks
        float4 blo = *(const float4*)&Bs[dd][tx * 4];
        float4 bhi = *(const float4*)&Bs[dd][128 + tx * 4];
        float a[8] = {alo.x, alo.y, alo.z, alo.w, ahi.x, ahi.y, ahi.z, ahi.w};
        float b[8] = {blo.x, blo.y, blo.z, blo.w, bhi.x, bhi.y, bhi.z, bhi.w};
#pragma unroll
        for (int i = 0; i < 8; ++i)
#pragma unroll
          for (int j = 0; j < 8; ++j)
            acc[i][j] = fmaf(a[i], b[j], acc[i][j]);
      }
    }

    // score with the reference's exact association: (xx - 2*dot) + vv
    // cols: j<4 -> kt*256 + tx*4 + j ; j>=4 -> kt*256 + 128 + tx*4 + (j-4)
    // visited in ascending col order per thread; strict < keeps first min
#pragma unroll
    for (int i = 0; i < 8; ++i) {
#pragma unroll
      for (int j = 0; j < 8; ++j) {
        int cloc = (j < 4) ? (tx * 4 + j) : (128 + tx * 4 + (j - 4));
        float s = __fadd_rn(__fsub_rn(xr[i], __fmul_rn(2.0f, acc[i][j])),
                            vvs[cloc]);
        int col = kt * 256 + cloc;
        if (s < best[i]) { best[i] = s; bidx[i] = col; }
      }
    }
  }

  // reduce (min, first-idx) across tx = lane bits 0..4 (stays within the wave)
#pragma unroll
  for (int off = 16; off >= 1; off >>= 1) {
#pragma unroll
    for (int i = 0; i < 8; ++i) {
      float ov = __shfl_xor(best[i], off);
      int   oi = __shfl_xor(bidx[i], off);
      if (ov < best[i] || (ov == best[i] && oi < bidx[i])) {
        best[i] = ov; bidx[i] = oi;
      }
    }
  }
  if (tx == 0) {
#pragma unroll
    for (int i = 0; i < 8; ++i)
      idx_out[row0 + ty * 8 + i] = (float)bidx[i];
  }
}

// ---------------- gather + STE + loss ----------------
__global__ __launch_bounds__(256) void vq_gather(const float* __restrict__ A,
                                                 const float* __restrict__ V,
                                                 const float* __restrict__ idxf,
                                                 float* __restrict__ outq,
                                                 float* __restrict__ loss_sum) {
  int e = blockIdx.x * 256 + threadIdx.x;  // float4 index
  int n = e >> 6;
  int c = (e & 63) << 2;
  int idx = (int)idxf[n];
  float4 xv = *(const float4*)(A + (size_t)n * D_DIM + c);
  float q0 = V[(size_t)(c + 0) * K_NUM + idx];
  float q1 = V[(size_t)(c + 1) * K_NUM + idx];
  float q2 = V[(size_t)(c + 2) * K_NUM + idx];
  float q3 = V[(size_t)(c + 3) * K_NUM + idx];
  float4 o;
  o.x = __fadd_rn(xv.x, __fsub_rn(q0, xv.x));  // x + (q - x), reference order
  o.y = __fadd_rn(xv.y, __fsub_rn(q1, xv.y));
  o.z = __fadd_rn(xv.z, __fsub_rn(q2, xv.z));
  o.w = __fadd_rn(xv.w, __fsub_rn(q3, xv.w));
  *(float4*)(outq + (size_t)n * D_DIM + c) = o;
  float d0 = __fsub_rn(xv.x, q0), d1 = __fsub_rn(xv.y, q1);
  float d2 = __fsub_rn(xv.z, q2), d3 = __fsub_rn(xv.w, q3);
  float ls = d0 * d0 + d1 * d1 + d2 * d2 + d3 * d3;

  __shared__ float red[256];
  red[threadIdx.x] = ls;
  __syncthreads();
  for (int s = 128; s > 0; s >>= 1) {
    if (threadIdx.x < s) red[threadIdx.x] += red[threadIdx.x + s];
    __syncthreads();
  }
  if (threadIdx.x == 0) atomicAdd(loss_sum, red[0]);
}

__global__ void vq_fin(const float* __restrict__ loss_sum,
                       float* __restrict__ out_losses) {
  float m = loss_sum[0] / 8388608.0f;
  out_losses[0] = m;  // dictionary_loss
  out_losses[1] = m;  // commitment_loss (numerically identical)
}

extern "C" void kernel_launch(void* const* d_in, const int* in_sizes, int n_in,
                              void* d_out, int out_size, void* d_ws, size_t ws_size,
                              hipStream_t stream) {
  const float* x = (const float*)d_in[0];
  const float* V = (const float*)d_in[1];
  float* out = (float*)d_out;
  float* outq    = out;                 // 8,388,608 floats
  float* outloss = out + 8388608;       // 2 floats
  float* outidx  = out + 8388610;       // 32,768 floats (indices as float)

  float* ws_vv  = (float*)d_ws;         // 4096 floats
  float* ws_sum = ws_vv + K_NUM;        // 1 float

  hipMemsetAsync(ws_sum, 0, sizeof(float), stream);
  vq_vv   <<<K_NUM / 256, 256, 0, stream>>>(V, ws_vv);
  vq_main <<<N_ROWS / 64, 256, 0, stream>>>(x, V, ws_vv, outidx);
  vq_gather<<<(N_ROWS * (D_DIM / 4)) / 256, 256, 0, stream>>>(x, V, outidx, outq, ws_sum);
  vq_fin  <<<1, 1, 0, stream>>>(ws_sum, outloss);
}

// Round 2
// 432.118 us; speedup vs baseline: 2.5255x; 2.5255x over previous
//
#include <hip/hip_runtime.h>
#include <math.h>

#define D_DIM 256
#define K_NUM 4096
#define N_ROWS 32768
#define QCAP 512
#define MARGIN 0.02f

typedef _Float16 half8 __attribute__((ext_vector_type(8)));
typedef float floatx4 __attribute__((ext_vector_type(4)));

// ---------------- vv[k] = sum_d V[d][k]^2 (same as passing round-1 kernel) ----
__global__ __launch_bounds__(256) void vq_vv(const float* __restrict__ V,
                                             float* __restrict__ vv) {
  int k = blockIdx.x * 256 + threadIdx.x;
  float acc = 0.0f;
  for (int d = 0; d < D_DIM; ++d) {
    float v = V[(size_t)d * K_NUM + k];
    acc = __fadd_rn(acc, __fmul_rn(v, v));
  }
  vv[k] = acc;
}

// numpy pairwise sum-of-squares over 128 floats, float4 loads, exact order
__device__ inline float np_pw128_sumsq(const float* __restrict__ p) {
  float r[8];
  float4 a = *(const float4*)p, b = *(const float4*)(p + 4);
  r[0] = __fmul_rn(a.x, a.x); r[1] = __fmul_rn(a.y, a.y);
  r[2] = __fmul_rn(a.z, a.z); r[3] = __fmul_rn(a.w, a.w);
  r[4] = __fmul_rn(b.x, b.x); r[5] = __fmul_rn(b.y, b.y);
  r[6] = __fmul_rn(b.z, b.z); r[7] = __fmul_rn(b.w, b.w);
#pragma unroll
  for (int i = 8; i < 128; i += 8) {
    a = *(const float4*)(p + i); b = *(const float4*)(p + i + 4);
    r[0] = __fadd_rn(r[0], __fmul_rn(a.x, a.x));
    r[1] = __fadd_rn(r[1], __fmul_rn(a.y, a.y));
    r[2] = __fadd_rn(r[2], __fmul_rn(a.z, a.z));
    r[3] = __fadd_rn(r[3], __fmul_rn(a.w, a.w));
    r[4] = __fadd_rn(r[4], __fmul_rn(b.x, b.x));
    r[5] = __fadd_rn(r[5], __fmul_rn(b.y, b.y));
    r[6] = __fadd_rn(r[6], __fmul_rn(b.z, b.z));
    r[7] = __fadd_rn(r[7], __fmul_rn(b.w, b.w));
  }
  float t01 = __fadd_rn(r[0], r[1]);
  float t23 = __fadd_rn(r[2], r[3]);
  float t45 = __fadd_rn(r[4], r[5]);
  float t67 = __fadd_rn(r[6], r[7]);
  return __fadd_rn(__fadd_rn(t01, t23), __fadd_rn(t45, t67));
}

__global__ __launch_bounds__(256) void vq_xx(const float* __restrict__ X,
                                             float* __restrict__ xx) {
  int n = blockIdx.x * 256 + threadIdx.x;
  const float* p = X + (size_t)n * D_DIM;
  xx[n] = __fadd_rn(np_pw128_sumsq(p), np_pw128_sumsq(p + 128));
}

// V [256][4096] f32 -> VtB f16, layout [d/8][col][d%8] (16B per (dchunk,col))
__global__ __launch_bounds__(256) void vq_vt(const float* __restrict__ V,
                                             _Float16* __restrict__ vtb) {
  int gid = blockIdx.x * 256 + threadIdx.x;   // 131072 threads
  int col = gid & (K_NUM - 1);
  int dc = gid >> 12;                          // 0..31
  half8 h;
#pragma unroll
  for (int j = 0; j < 8; ++j)
    h[j] = (_Float16)V[(size_t)(dc * 8 + j) * K_NUM + col];
  *(half8*)(vtb + ((size_t)dc * K_NUM + col) * 8) = h;
}

// ---------------- fp16 MFMA screen + margin-collect + exact rescore ----------
struct alignas(16) ScreenShared {
  _Float16 a[64 * 256];     // swizzled A tile, 32 KB
  float xxs[64];
  float wmin[8][64];
  float rowmin[64];
  unsigned qbuf[QCAP];
  float qscore[QCAP];
  int qn;
};

template <int PASS>
__device__ __forceinline__ void vq_sweep(ScreenShared& sh,
                                         const _Float16* __restrict__ vtb,
                                         const float* __restrict__ vvp,
                                         const float* xr, const float* rm,
                                         int w, int l) {
  const int g = l >> 4, ln = l & 15;
  for (int c = 0; c < 8; ++c) {
    const int cb = c * 512 + w * 64;
    floatx4 acc[4][4];
#pragma unroll
    for (int rf = 0; rf < 4; ++rf)
#pragma unroll
      for (int cf = 0; cf < 4; ++cf) acc[rf][cf] = {0.f, 0.f, 0.f, 0.f};

#pragma unroll
    for (int ks = 0; ks < 8; ++ks) {
      const int s0 = ks * 4 + g;               // 16B d-chunk index, 0..31
      half8 af[4], bf[4];
#pragma unroll
      for (int rf = 0; rf < 4; ++rf) {
        int r = rf * 16 + ln;
        int slot = (r << 5) | (s0 ^ ((r & 7) << 2));   // XOR-swizzle (T2)
        af[rf] = *(const half8*)&sh.a[slot * 8];
      }
#pragma unroll
      for (int cf = 0; cf < 4; ++cf) {
        int col = cb + cf * 16 + ln;
        bf[cf] = *(const half8*)(vtb + ((size_t)s0 * K_NUM + col) * 8);
      }
#pragma unroll
      for (int rf = 0; rf < 4; ++rf)
#pragma unroll
        for (int cf = 0; cf < 4; ++cf)
          acc[rf][cf] = __builtin_amdgcn_mfma_f32_16x16x32_f16(
              af[rf], bf[cf], acc[rf][cf], 0, 0, 0);
    }

    float vvc[4];
#pragma unroll
    for (int cf = 0; cf < 4; ++cf) vvc[cf] = vvp[cb + cf * 16 + ln];

#pragma unroll
    for (int rf = 0; rf < 4; ++rf) {
#pragma unroll
      for (int reg = 0; reg < 4; ++reg) {
        const int r = rf * 16 + g * 4 + reg;   // C/D row map (m89)
        if (PASS == 1) {
          float m = INFINITY;
#pragma unroll
          for (int cf = 0; cf < 4; ++cf) {
            float s = __fadd_rn(
                __fsub_rn(xr[rf * 4 + reg], __fmul_rn(2.0f, acc[rf][cf][reg])),
                vvc[cf]);
            m = fminf(m, s);
          }
#pragma unroll
          for (int off = 1; off <= 8; off <<= 1)
            m = fminf(m, __shfl_xor(m, off));
          if (ln == 0) sh.wmin[w][r] = fminf(sh.wmin[w][r], m);
        } else {
          const float thr = rm[rf * 4 + reg];
#pragma unroll
          for (int cf = 0; cf < 4; ++cf) {
            float s = __fadd_rn(
                __fsub_rn(xr[rf * 4 + reg], __fmul_rn(2.0f, acc[rf][cf][reg])),
                vvc[cf]);
            if (s <= thr) {
              int u = atomicAdd(&sh.qn, 1);
              if (u < QCAP)
                sh.qbuf[u] = ((unsigned)r << 12) | (unsigned)(cb + cf * 16 + ln);
            }
          }
        }
      }
    }
  }
}

__global__ __launch_bounds__(512, 2) void vq_screen(
    const float* __restrict__ X, const float* __restrict__ V,
    const _Float16* __restrict__ vtb, const float* __restrict__ vvp,
    const float* __restrict__ xxp, float* __restrict__ idx_out) {
  __shared__ ScreenShared sh;
  const int tid = threadIdx.x;
  const int w = tid >> 6, l = tid & 63;
  const int row0 = blockIdx.x * 64;

  // stage A: f32 -> f16, XOR-swizzled [64 rows][32 x 16B slots]
#pragma unroll
  for (int it = 0; it < 4; ++it) {
    int idx = it * 512 + tid;
    int r = idx >> 5, s = idx & 31;
    const float* xp = X + (size_t)(row0 + r) * D_DIM + s * 8;
    float4 v0 = *(const float4*)xp, v1 = *(const float4*)(xp + 4);
    half8 h;
    h[0] = (_Float16)v0.x; h[1] = (_Float16)v0.y;
    h[2] = (_Float16)v0.z; h[3] = (_Float16)v0.w;
    h[4] = (_Float16)v1.x; h[5] = (_Float16)v1.y;
    h[6] = (_Float16)v1.z; h[7] = (_Float16)v1.w;
    int slot = (r << 5) | (s ^ ((r & 7) << 2));
    *(half8*)&sh.a[slot * 8] = h;
  }
  if (tid < 64) sh.xxs[tid] = xxp[row0 + tid];
  sh.wmin[tid >> 6][tid & 63] = INFINITY;
  if (tid == 0) sh.qn = 0;
  __syncthreads();

  float xr[16];
#pragma unroll
  for (int rf = 0; rf < 4; ++rf)
#pragma unroll
    for (int reg = 0; reg < 4; ++reg)
      xr[rf * 4 + reg] = sh.xxs[rf * 16 + ((l >> 4) << 2) + reg];

  vq_sweep<1>(sh, vtb, vvp, xr, nullptr, w, l);
  __syncthreads();
  if (tid < 64) {
    float m = INFINITY;
#pragma unroll
    for (int j = 0; j < 8; ++j) m = fminf(m, sh.wmin[j][tid]);
    sh.rowmin[tid] = m;
  }
  __syncthreads();
  float rm[16];
#pragma unroll
  for (int rf = 0; rf < 4; ++rf)
#pragma unroll
    for (int reg = 0; reg < 4; ++reg)
      rm[rf * 4 + reg] =
          sh.rowmin[rf * 16 + ((l >> 4) << 2) + reg] + MARGIN;

  vq_sweep<2>(sh, vtb, vvp, xr, rm, w, l);
  __syncthreads();

  // exact fp32 rescore of candidates, one wave per entry
  const int nq = min(sh.qn, QCAP);
  for (int i = w; i < nq; i += 8) {
    unsigned e = sh.qbuf[i];
    int r = (int)(e >> 12), col = (int)(e & 4095);
    float4 xv = *(const float4*)(X + (size_t)(row0 + r) * D_DIM + l * 4);
    const float* vp = V + col;
    float p = 0.f;
    p = fmaf(xv.x, vp[(size_t)(l * 4 + 0) * K_NUM], p);
    p = fmaf(xv.y, vp[(size_t)(l * 4 + 1) * K_NUM], p);
    p = fmaf(xv.z, vp[(size_t)(l * 4 + 2) * K_NUM], p);
    p = fmaf(xv.w, vp[(size_t)(l * 4 + 3) * K_NUM], p);
#pragma unroll
    for (int off = 1; off < 64; off <<= 1) p += __shfl_xor(p, off);
    float s = __fadd_rn(__fsub_rn(sh.xxs[r], __fmul_rn(2.0f, p)), vvp[col]);
    if (l == 0) sh.qscore[i] = s;
  }
  __syncthreads();

  // per-row final argmin over candidates, tie -> smaller col (numpy semantics)
  if (tid < 64) {
    float b = INFINITY;
    int bi = 1 << 30;
    for (int i = 0; i < nq; ++i) {
      unsigned e = sh.qbuf[i];
      if ((int)(e >> 12) == tid) {
        int col = (int)(e & 4095);
        float s = sh.qscore[i];
        if (s < b || (s == b && col < bi)) { b = s; bi = col; }
      }
    }
    idx_out[row0 + tid] = (float)bi;
  }
}

// ---------------- gather + STE + loss (unchanged, passed round 1) ------------
__global__ __launch_bounds__(256) void vq_gather(const float* __restrict__ A,
                                                 const float* __restrict__ V,
                                                 const float* __restrict__ idxf,
                                                 float* __restrict__ outq,
                                                 float* __restrict__ loss_sum) {
  int e = blockIdx.x * 256 + threadIdx.x;  // float4 index
  int n = e >> 6;
  int c = (e & 63) << 2;
  int idx = (int)idxf[n];
  float4 xv = *(const float4*)(A + (size_t)n * D_DIM + c);
  float q0 = V[(size_t)(c + 0) * K_NUM + idx];
  float q1 = V[(size_t)(c + 1) * K_NUM + idx];
  float q2 = V[(size_t)(c + 2) * K_NUM + idx];
  float q3 = V[(size_t)(c + 3) * K_NUM + idx];
  float4 o;
  o.x = __fadd_rn(xv.x, __fsub_rn(q0, xv.x));
  o.y = __fadd_rn(xv.y, __fsub_rn(q1, xv.y));
  o.z = __fadd_rn(xv.z, __fsub_rn(q2, xv.z));
  o.w = __fadd_rn(xv.w, __fsub_rn(q3, xv.w));
  *(float4*)(outq + (size_t)n * D_DIM + c) = o;
  float d0 = __fsub_rn(xv.x, q0), d1 = __fsub_rn(xv.y, q1);
  float d2 = __fsub_rn(xv.z, q2), d3 = __fsub_rn(xv.w, q3);
  float ls = d0 * d0 + d1 * d1 + d2 * d2 + d3 * d3;

  __shared__ float red[256];
  red[threadIdx.x] = ls;
  __syncthreads();
  for (int s = 128; s > 0; s >>= 1) {
    if (threadIdx.x < s) red[threadIdx.x] += red[threadIdx.x + s];
    __syncthreads();
  }
  if (threadIdx.x == 0) atomicAdd(loss_sum, red[0]);
}

__global__ void vq_fin(const float* __restrict__ loss_sum,
                       float* __restrict__ out_losses) {
  float m = loss_sum[0] / 8388608.0f;
  out_losses[0] = m;
  out_losses[1] = m;
}

extern "C" void kernel_launch(void* const* d_in, const int* in_sizes, int n_in,
                              void* d_out, int out_size, void* d_ws, size_t ws_size,
                              hipStream_t stream) {
  const float* x = (const float*)d_in[0];
  const float* V = (const float*)d_in[1];
  float* out = (float*)d_out;
  float* outq    = out;
  float* outloss = out + 8388608;
  float* outidx  = out + 8388610;

  float* ws_vv  = (float*)d_ws;                     // 4096 f32
  float* ws_xx  = ws_vv + K_NUM;                    // 32768 f32
  float* ws_sum = ws_xx + N_ROWS;                   // 1 f32
  _Float16* ws_vt = (_Float16*)((char*)d_ws + 163840);  // 2 MB, 16B-aligned

  hipMemsetAsync(ws_sum, 0, sizeof(float), stream);
  vq_vv    <<<K_NUM / 256, 256, 0, stream>>>(V, ws_vv);
  vq_xx    <<<N_ROWS / 256, 256, 0, stream>>>(x, ws_xx);
  vq_vt    <<<(K_NUM * 32) / 256, 256, 0, stream>>>(V, ws_vt);
  vq_screen<<<N_ROWS / 64, 512, 0, stream>>>(x, V, ws_vt, ws_vv, ws_xx, outidx);
  vq_gather<<<(N_ROWS * (D_DIM / 4)) / 256, 256, 0, stream>>>(x, V, outidx, outq, ws_sum);
  vq_fin   <<<1, 1, 0, stream>>>(ws_sum, outloss);
}